// Round 11
// baseline (549.000 us; speedup 1.0000x reference)
//
#include <hip/hip_runtime.h>
#include <hip/hip_fp16.h>

#define TT 512
#define HH 128

typedef _Float16 half2_t __attribute__((ext_vector_type(2)));
typedef _Float16 half4_t __attribute__((ext_vector_type(4)));
typedef _Float16 half8_t __attribute__((ext_vector_type(8)));
typedef float    float4_t __attribute__((ext_vector_type(4)));

__device__ __forceinline__ half2_t pkrtz(float a, float b) {
    return __builtin_bit_cast(half2_t, __builtin_amdgcn_cvt_pkrtz(a, b));
}

// ---- trans-pipe activations. Weights/bias prescaled by -log2e (i,f,o rows)
// and -2log2e (g rows), so u = MFMA + xp directly feeds exp2:
//   sigma(x) = 1/(1+2^u),  tanh(x) = 2/(1+2^u) - 1.
// exp2 overflow gives natural saturation -> no clamps needed.
__device__ __forceinline__ float exp2_hw(float x) {
#if __has_builtin(__builtin_amdgcn_exp2f)
    return __builtin_amdgcn_exp2f(x);
#else
    float r; asm("v_exp_f32 %0, %1" : "=v"(r) : "v"(x)); return r;
#endif
}
__device__ __forceinline__ float rcp_hw(float x) {
#if __has_builtin(__builtin_amdgcn_rcpf)
    return __builtin_amdgcn_rcpf(x);
#else
    float r; asm("v_rcp_f32 %0, %1" : "=v"(r) : "v"(x)); return r;
#endif
}
__device__ __forceinline__ float sig_u(float u) {   // u = -L*x
    return rcp_hw(1.0f + exp2_hw(u));
}
__device__ __forceinline__ float tanh_u(float u) {  // u = -2L*x
    return 2.0f * rcp_hw(1.0f + exp2_hw(u)) - 1.0f;
}

#define SCL (-1.44269504088896340736f)   // -log2(e)  : i, f, o gate rows
#define SCG (-2.88539008177792681472f)   // -2log2(e) : g gate rows

// LDS-only barrier: waits lgkmcnt(0), leaves global loads/stores in flight.
__device__ __forceinline__ void wg_barrier_lds() {
#if __has_builtin(__builtin_amdgcn_s_waitcnt)
    __builtin_amdgcn_s_waitcnt(0xC07F);   // lgkmcnt(0), vmcnt=max, expcnt=max
#else
    asm volatile("s_waitcnt lgkmcnt(0)" ::: "memory");
#endif
    __builtin_amdgcn_s_barrier();
}

// xp layout (f16, PRESCALED): half index = (((dirbg*512 + t)*8 + w)*64+lane)*16,
// D-order [T*4+r]: Qa = {i r0..3, f r0..3}, Qb = {g r0..3, o r0..3}.
__device__ __forceinline__ size_t xp_off(int dirbg, int t, int w, int lane) {
    return (((size_t)dirbg * 512 + t) * 8 + w) * 1024 + (size_t)lane * 16;
}

// ---- kernel 1: xp GEMM (r21 conflict-free LDS). r22 change: awih and bias
// prescaled by SCL/SCG so xp comes out in exp2-ready units.
__global__ __attribute__((amdgpu_flat_work_group_size(512, 512), amdgpu_waves_per_eu(2, 2)))
void xp_gemm_kernel(
    const int* __restrict__ x, const float* __restrict__ emb,
    const float* __restrict__ Wih_f, const float* __restrict__ bih_f, const float* __restrict__ bhh_f,
    const float* __restrict__ Wih_b, const float* __restrict__ bih_b, const float* __restrict__ bhh_b,
    _Float16* __restrict__ xp)
{
    const int wg  = blockIdx.x;        // dirbg
    const int dir = wg >> 3, bg = wg & 7;
    const int tb0 = blockIdx.y * 32;   // t-base (32 steps per block)

    const float* Wih = dir ? Wih_b : Wih_f;
    const float* bih = dir ? bih_b : bih_f;
    const float* bhh = dir ? bhh_b : bhh_f;

    const int tid = threadIdx.x;
    const int w = tid >> 6, lane = tid & 63, lq = lane >> 4, lm = lane & 15;

    __shared__ int id_sm[512];            // [t_local][chain]
    __shared__ _Float16 Esm[16 * 2048];   // [tile][kk*512 + lane*8 + j]

    id_sm[tid] = x[(size_t)(bg * 16 + (tid & 15)) * TT + tb0 + (tid >> 4)];

    half8_t awih[4][4];
    #pragma unroll
    for (int T = 0; T < 4; ++T) {
        const float sc = (T == 2) ? SCG : SCL;
        #pragma unroll
        for (int kk = 0; kk < 4; ++kk) {
            const float4* s = (const float4*)(Wih + (size_t)(T * 128 + w * 16 + lm) * 128 + kk * 32 + lq * 8);
            float4 v0 = s[0], v1 = s[1];
            half8_t h;
            half2_t a = pkrtz(v0.x * sc, v0.y * sc), b = pkrtz(v0.z * sc, v0.w * sc);
            half2_t c = pkrtz(v1.x * sc, v1.y * sc), d = pkrtz(v1.z * sc, v1.w * sc);
            h[0]=a[0]; h[1]=a[1]; h[2]=b[0]; h[3]=b[1];
            h[4]=c[0]; h[5]=c[1]; h[6]=d[0]; h[7]=d[1];
            awih[T][kk] = h;
        }
    }
    float4_t biasv[4];
    #pragma unroll
    for (int T = 0; T < 4; ++T) {
        const float sc = (T == 2) ? SCG : SCL;
        int g = T * 128 + w * 16 + lq * 4;
        float4 b1 = *(const float4*)(bih + g);
        float4 b2 = *(const float4*)(bhh + g);
        biasv[T] = (float4_t){(b1.x + b2.x) * sc, (b1.y + b2.y) * sc,
                              (b1.z + b2.z) * sc, (b1.w + b2.w) * sc};
    }

    #pragma unroll 1
    for (int hlf = 0; hlf < 2; ++hlf) {
        __syncthreads();

        {   // stage: wave w fills (tile,kk) blocks {2w,2w+1} x {0..3}
            #pragma unroll
            for (int m = 0; m < 8; ++m) {
                const int ti = w * 2 + (m >> 2);
                const int kk = m & 3;
                const int id = id_sm[(hlf * 16 + ti) * 16 + lm];
                const float* src = emb + (size_t)id * 128 + kk * 32 + lq * 8;
                float4 v0 = *(const float4*)(src);
                float4 v1 = *(const float4*)(src + 4);
                half2_t a = pkrtz(v0.x, v0.y), b = pkrtz(v0.z, v0.w);
                half2_t c = pkrtz(v1.x, v1.y), d = pkrtz(v1.z, v1.w);
                half8_t h8;
                h8[0]=a[0]; h8[1]=a[1]; h8[2]=b[0]; h8[3]=b[1];
                h8[4]=c[0]; h8[5]=c[1]; h8[6]=d[0]; h8[7]=d[1];
                *(half8_t*)&Esm[ti * 2048 + kk * 512 + lane * 8] = h8;
            }
        }
        __syncthreads();

        const int tb = tb0 + hlf * 16;
        #pragma unroll 4
        for (int i = 0; i < 16; ++i) {
            const _Float16* eb = &Esm[i * 2048 + lane * 8];
            half8_t bfr0 = *(const half8_t*)(eb);
            half8_t bfr1 = *(const half8_t*)(eb + 512);
            half8_t bfr2 = *(const half8_t*)(eb + 1024);
            half8_t bfr3 = *(const half8_t*)(eb + 1536);

            float4_t acc[4];
            #pragma unroll
            for (int T = 0; T < 4; ++T) acc[T] = biasv[T];
            #pragma unroll
            for (int T = 0; T < 4; ++T)
                acc[T] = __builtin_amdgcn_mfma_f32_16x16x32_f16(awih[T][0], bfr0, acc[T], 0, 0, 0);
            #pragma unroll
            for (int T = 0; T < 4; ++T)
                acc[T] = __builtin_amdgcn_mfma_f32_16x16x32_f16(awih[T][1], bfr1, acc[T], 0, 0, 0);
            #pragma unroll
            for (int T = 0; T < 4; ++T)
                acc[T] = __builtin_amdgcn_mfma_f32_16x16x32_f16(awih[T][2], bfr2, acc[T], 0, 0, 0);
            #pragma unroll
            for (int T = 0; T < 4; ++T)
                acc[T] = __builtin_amdgcn_mfma_f32_16x16x32_f16(awih[T][3], bfr3, acc[T], 0, 0, 0);

            half8_t p0, p1;
            {
                half2_t a = pkrtz(acc[0][0], acc[0][1]), b = pkrtz(acc[0][2], acc[0][3]);
                half2_t c = pkrtz(acc[1][0], acc[1][1]), d = pkrtz(acc[1][2], acc[1][3]);
                p0[0]=a[0]; p0[1]=a[1]; p0[2]=b[0]; p0[3]=b[1];
                p0[4]=c[0]; p0[5]=c[1]; p0[6]=d[0]; p0[7]=d[1];
            }
            {
                half2_t a = pkrtz(acc[2][0], acc[2][1]), b = pkrtz(acc[2][2], acc[2][3]);
                half2_t c = pkrtz(acc[3][0], acc[3][1]), d = pkrtz(acc[3][2], acc[3][3]);
                p1[0]=a[0]; p1[1]=a[1]; p1[2]=b[0]; p1[3]=b[1];
                p1[4]=c[0]; p1[5]=c[1]; p1[6]=d[0]; p1[7]=d[1];
            }
            half8_t* dst = (half8_t*)(xp + xp_off(wg, tb + i, w, lane));
            dst[0] = p0; dst[1] = p1;
        }
    }
}

// ---- kernel 2: recurrence (r22). Structure = r20 (fragment-linear hsm,
// interleaved MFMA/act schedule). Activation rewrite: f32 exp2/rcp on the
// TRANS pipe (idle until now) replaces the packed-f16 polynomial path.
// Whh prescaled by SCL/SCG; xp arrives prescaled; u = acc + xp feeds exp2
// directly; exp2 overflow = natural saturation (clamps deleted); cell
// state f32. ~100 VALU + 40 trans instr/thread/step vs ~160 VALU before.
__global__ __attribute__((amdgpu_flat_work_group_size(512, 512), amdgpu_waves_per_eu(2, 2)))
void bilstm_rec_kernel(
    const _Float16* __restrict__ xp,
    const float* __restrict__ Whh_f, const float* __restrict__ Whh_b,
    float* __restrict__ pooled)
{
    const int wg  = blockIdx.x;        // 0..15 dirbg
    const int dir = wg >> 3, bg = wg & 7;
    const float* Whh = dir ? Whh_b : Whh_f;

    const int tid = threadIdx.x;
    const int w = tid >> 6, lane = tid & 63, lq = lane >> 4, lm = lane & 15;

    __shared__ _Float16 hsm[2][2048];   // [buf][kk*512 + lane*8 + j] fragment-linear

    half8_t awhh[4][4];
    #pragma unroll
    for (int T = 0; T < 4; ++T) {
        const float sc = (T == 2) ? SCG : SCL;
        #pragma unroll
        for (int kk = 0; kk < 4; ++kk) {
            const float4* s = (const float4*)(Whh + (size_t)(T * 128 + w * 16 + lm) * 128 + kk * 32 + lq * 8);
            float4 v0 = s[0], v1 = s[1];
            half8_t h;
            half2_t a = pkrtz(v0.x * sc, v0.y * sc), b = pkrtz(v0.z * sc, v0.w * sc);
            half2_t c = pkrtz(v1.x * sc, v1.y * sc), d = pkrtz(v1.z * sc, v1.w * sc);
            h[0]=a[0]; h[1]=a[1]; h[2]=b[0]; h[3]=b[1];
            h[4]=c[0]; h[5]=c[1]; h[6]=d[0]; h[7]=d[1];
            awhh[T][kk] = h;
        }
    }

    for (int k = tid; k < 2 * 2048; k += 512)
        ((_Float16*)hsm)[k] = (_Float16)0.0f;

    const int rbase = lane * 8;
    const int wbase = (w >> 1) * 512 + ((w & 1) * 2 + (lq >> 1)) * 128 + lm * 8 + (lq & 1) * 4;

    const _Float16* xp_wl = xp + ((size_t)wg * 512 * 8 + w) * 1024 + (size_t)lane * 16;

    half8_t Qa[4], Qb[4];
    {
        int ta = dir ? (TT - 1) : 0;
        const half8_t* p = (const half8_t*)(xp_wl + (size_t)ta * 8192);
        Qa[0] = p[0]; Qb[0] = p[1];
    }
    {
        int ta = dir ? (TT - 2) : 1;
        const half8_t* p = (const half8_t*)(xp_wl + (size_t)ta * 8192);
        Qa[1] = p[0]; Qb[1] = p[1];
    }
    __syncthreads();

    const float4_t zz = {0.0f, 0.0f, 0.0f, 0.0f};
    float cc0 = 0.0f, cc1 = 0.0f, cc2 = 0.0f, cc3 = 0.0f;
    float hx0 = -1.0e30f, hx1 = -1.0e30f, hx2 = -1.0e30f, hx3 = -1.0e30f;

    for (int tbs = 0; tbs < TT; tbs += 4) {
        #pragma unroll
        for (int P = 0; P < 4; ++P) {
            const int t = tbs + P;
            {   // prefetch xp(t+2) into buffer (P+2)&3 (clamped, proven)
                int tl = (t + 2 < TT) ? (t + 2) : (TT - 1);
                int ta = dir ? (TT - 1 - tl) : tl;
                const half8_t* pp = (const half8_t*)(xp_wl + (size_t)ta * 8192);
                Qa[(P + 2) & 3] = pp[0]; Qb[(P + 2) & 3] = pp[1];
            }

            const _Float16* hb = &hsm[P & 1][rbase];
            half8_t bh0 = *(const half8_t*)(hb);
            half8_t bh1 = *(const half8_t*)(hb + 512);
            half8_t bh2 = *(const half8_t*)(hb + 1024);
            half8_t bh3 = *(const half8_t*)(hb + 1536);

            // ---- interleaved: MFMA chains followed by their activations ----
            float4_t a0 = __builtin_amdgcn_mfma_f32_16x16x32_f16(awhh[0][0], bh0, zz, 0, 0, 0);
            a0 = __builtin_amdgcn_mfma_f32_16x16x32_f16(awhh[0][1], bh1, a0, 0, 0, 0);
            a0 = __builtin_amdgcn_mfma_f32_16x16x32_f16(awhh[0][2], bh2, a0, 0, 0, 0);
            a0 = __builtin_amdgcn_mfma_f32_16x16x32_f16(awhh[0][3], bh3, a0, 0, 0, 0);
            float4_t a1 = __builtin_amdgcn_mfma_f32_16x16x32_f16(awhh[1][0], bh0, zz, 0, 0, 0);
            a1 = __builtin_amdgcn_mfma_f32_16x16x32_f16(awhh[1][1], bh1, a1, 0, 0, 0);
            a1 = __builtin_amdgcn_mfma_f32_16x16x32_f16(awhh[1][2], bh2, a1, 0, 0, 0);
            a1 = __builtin_amdgcn_mfma_f32_16x16x32_f16(awhh[1][3], bh3, a1, 0, 0, 0);

            float gi0 = sig_u(a0[0] + (float)Qa[P][0]);
            float gi1 = sig_u(a0[1] + (float)Qa[P][1]);
            float gi2 = sig_u(a0[2] + (float)Qa[P][2]);
            float gi3 = sig_u(a0[3] + (float)Qa[P][3]);

            float4_t a2 = __builtin_amdgcn_mfma_f32_16x16x32_f16(awhh[2][0], bh0, zz, 0, 0, 0);
            a2 = __builtin_amdgcn_mfma_f32_16x16x32_f16(awhh[2][1], bh1, a2, 0, 0, 0);
            a2 = __builtin_amdgcn_mfma_f32_16x16x32_f16(awhh[2][2], bh2, a2, 0, 0, 0);
            a2 = __builtin_amdgcn_mfma_f32_16x16x32_f16(awhh[2][3], bh3, a2, 0, 0, 0);

            float gf0 = sig_u(a1[0] + (float)Qa[P][4]);
            float gf1 = sig_u(a1[1] + (float)Qa[P][5]);
            float gf2 = sig_u(a1[2] + (float)Qa[P][6]);
            float gf3 = sig_u(a1[3] + (float)Qa[P][7]);

            float4_t a3 = __builtin_amdgcn_mfma_f32_16x16x32_f16(awhh[3][0], bh0, zz, 0, 0, 0);
            a3 = __builtin_amdgcn_mfma_f32_16x16x32_f16(awhh[3][1], bh1, a3, 0, 0, 0);
            a3 = __builtin_amdgcn_mfma_f32_16x16x32_f16(awhh[3][2], bh2, a3, 0, 0, 0);
            a3 = __builtin_amdgcn_mfma_f32_16x16x32_f16(awhh[3][3], bh3, a3, 0, 0, 0);

            float gg0 = tanh_u(a2[0] + (float)Qb[P][0]);
            float gg1 = tanh_u(a2[1] + (float)Qb[P][1]);
            float gg2 = tanh_u(a2[2] + (float)Qb[P][2]);
            float gg3 = tanh_u(a2[3] + (float)Qb[P][3]);

            float go0 = sig_u(a3[0] + (float)Qb[P][4]);
            float go1 = sig_u(a3[1] + (float)Qb[P][5]);
            float go2 = sig_u(a3[2] + (float)Qb[P][6]);
            float go3 = sig_u(a3[3] + (float)Qb[P][7]);

            cc0 = gf0 * cc0 + gi0 * gg0;
            cc1 = gf1 * cc1 + gi1 * gg1;
            cc2 = gf2 * cc2 + gi2 * gg2;
            cc3 = gf3 * cc3 + gi3 * gg3;

            float h0 = go0 * tanh_u(cc0 * SCG);
            float h1 = go1 * tanh_u(cc1 * SCG);
            float h2v = go2 * tanh_u(cc2 * SCG);
            float h3 = go3 * tanh_u(cc3 * SCG);

            hx0 = fmaxf(hx0, h0);
            hx1 = fmaxf(hx1, h1);
            hx2 = fmaxf(hx2, h2v);
            hx3 = fmaxf(hx3, h3);

            half2_t hA = pkrtz(h0, h1), hB = pkrtz(h2v, h3);
            half4_t hv4;
            hv4[0] = hA[0]; hv4[1] = hA[1]; hv4[2] = hB[0]; hv4[3] = hB[1];
            *(half4_t*)&hsm[1 - (P & 1)][wbase] = hv4;

            // schedule pins (best-effort; trans ops count as VALU mask 0x2)
            __builtin_amdgcn_sched_group_barrier(0x100, 4, 0);  // bh reads
            __builtin_amdgcn_sched_group_barrier(0x008, 4, 0);  // a0 chain
            __builtin_amdgcn_sched_group_barrier(0x008, 4, 0);  // a1 chain
            __builtin_amdgcn_sched_group_barrier(0x002, 18, 0); // i acts
            __builtin_amdgcn_sched_group_barrier(0x008, 4, 0);  // a2 chain
            __builtin_amdgcn_sched_group_barrier(0x002, 18, 0); // f acts
            __builtin_amdgcn_sched_group_barrier(0x008, 4, 0);  // a3 chain
            __builtin_amdgcn_sched_group_barrier(0x002, 18, 0); // g acts

            wg_barrier_lds();
        }
    }

    float4 o;
    o.x = hx0; o.y = hx1; o.z = hx2; o.w = hx3;
    *(float4*)&pooled[(size_t)(bg * 16 + lm) * 256 + dir * HH + w * 16 + lq * 4] = o;
}

// ---- kernel 3: pooled (128,256) -> relu(W1·+b1) -> sigmoid(W2·+b2) -> (128,1)
__global__ __launch_bounds__(64) void mlp_kernel(
    const float* __restrict__ pooled, const float* __restrict__ W1,
    const float* __restrict__ b1, const float* __restrict__ W2,
    const float* __restrict__ b2, float* __restrict__ out)
{
    const int b = blockIdx.x;
    const int j = threadIdx.x;
    const float4* p = (const float4*)(pooled + (size_t)b * 256);
    const float4* wv = (const float4*)(W1 + (size_t)j * 256);
    float s = 0.0f;
    #pragma unroll
    for (int q = 0; q < 64; ++q) {
        float4 pv = p[q];
        float4 ww = wv[q];
        s += pv.x * ww.x + pv.y * ww.y + pv.z * ww.z + pv.w * ww.w;
    }
    s += b1[j];
    s = fmaxf(s, 0.0f);
    float v = W2[j] * s;
    #pragma unroll
    for (int off = 32; off; off >>= 1) v += __shfl_down(v, off);
    if (j == 0) out[b] = 1.0f / (1.0f + __expf(-(v + b2[0])));
}

extern "C" void kernel_launch(void* const* d_in, const int* in_sizes, int n_in,
                              void* d_out, int out_size, void* d_ws, size_t ws_size,
                              hipStream_t stream) {
    const int*   x     = (const int*)d_in[0];
    const float* emb   = (const float*)d_in[1];
    const float* Wih_f = (const float*)d_in[2];
    const float* Whh_f = (const float*)d_in[3];
    const float* bih_f = (const float*)d_in[4];
    const float* bhh_f = (const float*)d_in[5];
    const float* Wih_b = (const float*)d_in[6];
    const float* Whh_b = (const float*)d_in[7];
    const float* bih_b = (const float*)d_in[8];
    const float* bhh_b = (const float*)d_in[9];
    const float* W1    = (const float*)d_in[10];
    const float* b1    = (const float*)d_in[11];
    const float* W2    = (const float*)d_in[12];
    const float* b2    = (const float*)d_in[13];
    float* out = (float*)d_out;

    char* ws = (char*)d_ws;
    float*    pooled = (float*)ws;                 // 128 KB
    _Float16* xp     = (_Float16*)(ws + 131072);   // 134.2 MB

    hipLaunchKernelGGL(xp_gemm_kernel, dim3(16, 16), dim3(512), 0, stream,
                       x, emb, Wih_f, bih_f, bhh_f, Wih_b, bih_b, bhh_b, xp);
    hipLaunchKernelGGL(bilstm_rec_kernel, dim3(16), dim3(512), 0, stream,
                       xp, Whh_f, Whh_b, pooled);
    hipLaunchKernelGGL(mlp_kernel, dim3(128), dim3(64), 0, stream,
                       pooled, W1, b1, W2, b2, out);
}

// Round 12
// 459.926 us; speedup vs baseline: 1.1937x; 1.1937x over previous
//
#include <hip/hip_runtime.h>
#include <hip/hip_fp16.h>

#define TT 512
#define HH 128

typedef _Float16 half2_t __attribute__((ext_vector_type(2)));
typedef _Float16 half4_t __attribute__((ext_vector_type(4)));
typedef _Float16 half8_t __attribute__((ext_vector_type(8)));
typedef float    float4_t __attribute__((ext_vector_type(4)));

__device__ __forceinline__ half2_t h2(float v) {
    half2_t r; r[0] = (_Float16)v; r[1] = (_Float16)v; return r;
}
__device__ __forceinline__ half2_t pkrtz(float a, float b) {
    return __builtin_bit_cast(half2_t, __builtin_amdgcn_cvt_pkrtz(a, b));
}

// ---- packed-f16 polynomial activations (no transcendentals).
// r22 lesson: scalar f32 + trans-pipe exp2/rcp INCREASED issue work (2x
// SIMD-width loss + converts); packed-f16 poly is the issue-minimal form.
#define TC1 0.994940f
#define TC3 -0.290799f
#define TC5 0.065507f
#define TC7 -0.0062464f
#define SC1 0.2487350f
#define SC3 -0.0181749f
#define SC5 0.00102355f
#define SC7 -0.0000244141f

__device__ __forceinline__ half2_t tanh_pk(half2_t x) {
    half2_t m = __builtin_elementwise_min(__builtin_elementwise_max(x, h2(-2.0f)), h2(2.0f));
    half2_t t = m * m;
    half2_t p = h2(TC7) * t + h2(TC5);
    p = p * t + h2(TC3);
    p = p * t + h2(TC1);
    return m * p;
}
__device__ __forceinline__ half2_t sigma_pk(half2_t x) {
    half2_t m = __builtin_elementwise_min(__builtin_elementwise_max(x, h2(-4.0f)), h2(4.0f));
    half2_t t = m * m;
    half2_t p = h2(SC7) * t + h2(SC5);
    p = p * t + h2(SC3);
    p = p * t + h2(SC1);
    return m * p + h2(0.5f);
}

// LDS-only barrier: waits lgkmcnt(0), leaves global loads/stores in flight.
__device__ __forceinline__ void wg_barrier_lds() {
#if __has_builtin(__builtin_amdgcn_s_waitcnt)
    __builtin_amdgcn_s_waitcnt(0xC07F);   // lgkmcnt(0), vmcnt=max, expcnt=max
#else
    asm volatile("s_waitcnt lgkmcnt(0)" ::: "memory");
#endif
    __builtin_amdgcn_s_barrier();
}

// xp layout (f16): half index = (((dirbg*512 + t)*8 + w)*64 + lane)*16,
// 16 halfs per (t,w,lane) in D-order [T*4+r]. Transposed MFMA convention:
// lane (lq,lm) holds gates T*128 + w*16 + lq*4 + r for chain bg*16+lm.
__device__ __forceinline__ size_t xp_off(int dirbg, int t, int w, int lane) {
    return (((size_t)dirbg * 512 + t) * 8 + w) * 1024 + (size_t)lane * 16;
}

// ---- kernel 1: xp GEMM (r21: conflict-free fragment-linear LDS both sides).
__global__ __attribute__((amdgpu_flat_work_group_size(512, 512), amdgpu_waves_per_eu(2, 2)))
void xp_gemm_kernel(
    const int* __restrict__ x, const float* __restrict__ emb,
    const float* __restrict__ Wih_f, const float* __restrict__ bih_f, const float* __restrict__ bhh_f,
    const float* __restrict__ Wih_b, const float* __restrict__ bih_b, const float* __restrict__ bhh_b,
    _Float16* __restrict__ xp)
{
    const int wg  = blockIdx.x;        // dirbg
    const int dir = wg >> 3, bg = wg & 7;
    const int tb0 = blockIdx.y * 32;   // t-base (32 steps per block)

    const float* Wih = dir ? Wih_b : Wih_f;
    const float* bih = dir ? bih_b : bih_f;
    const float* bhh = dir ? bhh_b : bhh_f;

    const int tid = threadIdx.x;
    const int w = tid >> 6, lane = tid & 63, lq = lane >> 4, lm = lane & 15;

    __shared__ int id_sm[512];            // [t_local 0..31][chain 0..15]
    __shared__ _Float16 Esm[16 * 2048];   // [tile][kk*512 + lane*8 + j] fragment-linear

    id_sm[tid] = x[(size_t)(bg * 16 + (tid & 15)) * TT + tb0 + (tid >> 4)];

    half8_t awih[4][4];
    #pragma unroll
    for (int T = 0; T < 4; ++T) {
        #pragma unroll
        for (int kk = 0; kk < 4; ++kk) {
            const float4* s = (const float4*)(Wih + (size_t)(T * 128 + w * 16 + lm) * 128 + kk * 32 + lq * 8);
            float4 v0 = s[0], v1 = s[1];
            half8_t h;
            half2_t a = pkrtz(v0.x, v0.y), b = pkrtz(v0.z, v0.w);
            half2_t c = pkrtz(v1.x, v1.y), d = pkrtz(v1.z, v1.w);
            h[0]=a[0]; h[1]=a[1]; h[2]=b[0]; h[3]=b[1];
            h[4]=c[0]; h[5]=c[1]; h[6]=d[0]; h[7]=d[1];
            awih[T][kk] = h;
        }
    }
    float4_t biasv[4];
    #pragma unroll
    for (int T = 0; T < 4; ++T) {
        int g = T * 128 + w * 16 + lq * 4;
        float4 b1 = *(const float4*)(bih + g);
        float4 b2 = *(const float4*)(bhh + g);
        biasv[T] = (float4_t){b1.x + b2.x, b1.y + b2.y, b1.z + b2.z, b1.w + b2.w};
    }

    #pragma unroll 1
    for (int hlf = 0; hlf < 2; ++hlf) {
        __syncthreads();   // id_sm ready (hlf 0) / prev-half Esm reads done (hlf 1)

        {   // stage: wave w fills (tile,kk) blocks {2w,2w+1} x {0..3};
            // each write = 64 lanes x b128 over a contiguous 1KB (conflict-free)
            #pragma unroll
            for (int m = 0; m < 8; ++m) {
                const int ti = w * 2 + (m >> 2);   // tile 0..15
                const int kk = m & 3;
                const int id = id_sm[(hlf * 16 + ti) * 16 + lm];
                const float* src = emb + (size_t)id * 128 + kk * 32 + lq * 8;
                float4 v0 = *(const float4*)(src);
                float4 v1 = *(const float4*)(src + 4);
                half2_t a = pkrtz(v0.x, v0.y), b = pkrtz(v0.z, v0.w);
                half2_t c = pkrtz(v1.x, v1.y), d = pkrtz(v1.z, v1.w);
                half8_t h8;
                h8[0]=a[0]; h8[1]=a[1]; h8[2]=b[0]; h8[3]=b[1];
                h8[4]=c[0]; h8[5]=c[1]; h8[6]=d[0]; h8[7]=d[1];
                *(half8_t*)&Esm[ti * 2048 + kk * 512 + lane * 8] = h8;
            }
        }
        __syncthreads();   // Esm ready; read-only in compute phase

        const int tb = tb0 + hlf * 16;
        #pragma unroll 4
        for (int i = 0; i < 16; ++i) {
            const _Float16* eb = &Esm[i * 2048 + lane * 8];
            half8_t bfr0 = *(const half8_t*)(eb);
            half8_t bfr1 = *(const half8_t*)(eb + 512);
            half8_t bfr2 = *(const half8_t*)(eb + 1024);
            half8_t bfr3 = *(const half8_t*)(eb + 1536);

            float4_t acc[4];
            #pragma unroll
            for (int T = 0; T < 4; ++T) acc[T] = biasv[T];
            #pragma unroll
            for (int T = 0; T < 4; ++T)
                acc[T] = __builtin_amdgcn_mfma_f32_16x16x32_f16(awih[T][0], bfr0, acc[T], 0, 0, 0);
            #pragma unroll
            for (int T = 0; T < 4; ++T)
                acc[T] = __builtin_amdgcn_mfma_f32_16x16x32_f16(awih[T][1], bfr1, acc[T], 0, 0, 0);
            #pragma unroll
            for (int T = 0; T < 4; ++T)
                acc[T] = __builtin_amdgcn_mfma_f32_16x16x32_f16(awih[T][2], bfr2, acc[T], 0, 0, 0);
            #pragma unroll
            for (int T = 0; T < 4; ++T)
                acc[T] = __builtin_amdgcn_mfma_f32_16x16x32_f16(awih[T][3], bfr3, acc[T], 0, 0, 0);

            half8_t p0, p1;
            {
                half2_t a = pkrtz(acc[0][0], acc[0][1]), b = pkrtz(acc[0][2], acc[0][3]);
                half2_t c = pkrtz(acc[1][0], acc[1][1]), d = pkrtz(acc[1][2], acc[1][3]);
                p0[0]=a[0]; p0[1]=a[1]; p0[2]=b[0]; p0[3]=b[1];
                p0[4]=c[0]; p0[5]=c[1]; p0[6]=d[0]; p0[7]=d[1];
            }
            {
                half2_t a = pkrtz(acc[2][0], acc[2][1]), b = pkrtz(acc[2][2], acc[2][3]);
                half2_t c = pkrtz(acc[3][0], acc[3][1]), d = pkrtz(acc[3][2], acc[3][3]);
                p1[0]=a[0]; p1[1]=a[1]; p1[2]=b[0]; p1[3]=b[1];
                p1[4]=c[0]; p1[5]=c[1]; p1[6]=d[0]; p1[7]=d[1];
            }
            half8_t* dst = (half8_t*)(xp + xp_off(wg, tb + i, w, lane));
            dst[0] = p0; dst[1] = p1;
        }
    }
}

// ---- kernel 2: recurrence (r20 frozen: fragment-linear hsm + interleaved
// MFMA/activation schedule pinned with sched_group_barrier; proven 314.5us).
__global__ __attribute__((amdgpu_flat_work_group_size(512, 512), amdgpu_waves_per_eu(2, 2)))
void bilstm_rec_kernel(
    const _Float16* __restrict__ xp,
    const float* __restrict__ Whh_f, const float* __restrict__ Whh_b,
    float* __restrict__ pooled)
{
    const int wg  = blockIdx.x;        // 0..15 dirbg
    const int dir = wg >> 3, bg = wg & 7;
    const float* Whh = dir ? Whh_b : Whh_f;

    const int tid = threadIdx.x;
    const int w = tid >> 6, lane = tid & 63, lq = lane >> 4, lm = lane & 15;

    __shared__ _Float16 hsm[2][2048];   // [buf][kk*512 + lane*8 + j] fragment-linear

    half8_t awhh[4][4];
    #pragma unroll
    for (int T = 0; T < 4; ++T) {
        #pragma unroll
        for (int kk = 0; kk < 4; ++kk) {
            const float4* s = (const float4*)(Whh + (size_t)(T * 128 + w * 16 + lm) * 128 + kk * 32 + lq * 8);
            float4 v0 = s[0], v1 = s[1];
            half8_t h;
            half2_t a = pkrtz(v0.x, v0.y), b = pkrtz(v0.z, v0.w);
            half2_t c = pkrtz(v1.x, v1.y), d = pkrtz(v1.z, v1.w);
            h[0]=a[0]; h[1]=a[1]; h[2]=b[0]; h[3]=b[1];
            h[4]=c[0]; h[5]=c[1]; h[6]=d[0]; h[7]=d[1];
            awhh[T][kk] = h;
        }
    }

    for (int k = tid; k < 2 * 2048; k += 512)
        ((_Float16*)hsm)[k] = (_Float16)0.0f;

    const int rbase = lane * 8;
    const int wbase = (w >> 1) * 512 + ((w & 1) * 2 + (lq >> 1)) * 128 + lm * 8 + (lq & 1) * 4;

    const _Float16* xp_wl = xp + ((size_t)wg * 512 * 8 + w) * 1024 + (size_t)lane * 16;

    half8_t Qa[4], Qb[4];
    {
        int ta = dir ? (TT - 1) : 0;
        const half8_t* p = (const half8_t*)(xp_wl + (size_t)ta * 8192);
        Qa[0] = p[0]; Qb[0] = p[1];
    }
    {
        int ta = dir ? (TT - 2) : 1;
        const half8_t* p = (const half8_t*)(xp_wl + (size_t)ta * 8192);
        Qa[1] = p[0]; Qb[1] = p[1];
    }
    __syncthreads();

    const float4_t zz = {0.0f, 0.0f, 0.0f, 0.0f};
    half2_t c01 = h2(0.0f), c23 = h2(0.0f);
    half2_t hm01 = h2(-60000.0f), hm23 = h2(-60000.0f);

    for (int tbs = 0; tbs < TT; tbs += 4) {
        #pragma unroll
        for (int P = 0; P < 4; ++P) {
            const int t = tbs + P;
            {   // prefetch xp(t+2) into buffer (P+2)&3 (clamped, proven)
                int tl = (t + 2 < TT) ? (t + 2) : (TT - 1);
                int ta = dir ? (TT - 1 - tl) : tl;
                const half8_t* pp = (const half8_t*)(xp_wl + (size_t)ta * 8192);
                Qa[(P + 2) & 3] = pp[0]; Qb[(P + 2) & 3] = pp[1];
            }

            const _Float16* hb = &hsm[P & 1][rbase];
            half8_t bh0 = *(const half8_t*)(hb);
            half8_t bh1 = *(const half8_t*)(hb + 512);
            half8_t bh2 = *(const half8_t*)(hb + 1024);
            half8_t bh3 = *(const half8_t*)(hb + 1536);

            // ---- interleaved schedule: acc chains followed by their acts ----
            float4_t a0 = __builtin_amdgcn_mfma_f32_16x16x32_f16(awhh[0][0], bh0, zz, 0, 0, 0);
            a0 = __builtin_amdgcn_mfma_f32_16x16x32_f16(awhh[0][1], bh1, a0, 0, 0, 0);
            a0 = __builtin_amdgcn_mfma_f32_16x16x32_f16(awhh[0][2], bh2, a0, 0, 0, 0);
            a0 = __builtin_amdgcn_mfma_f32_16x16x32_f16(awhh[0][3], bh3, a0, 0, 0, 0);
            float4_t a1 = __builtin_amdgcn_mfma_f32_16x16x32_f16(awhh[1][0], bh0, zz, 0, 0, 0);
            a1 = __builtin_amdgcn_mfma_f32_16x16x32_f16(awhh[1][1], bh1, a1, 0, 0, 0);
            a1 = __builtin_amdgcn_mfma_f32_16x16x32_f16(awhh[1][2], bh2, a1, 0, 0, 0);
            a1 = __builtin_amdgcn_mfma_f32_16x16x32_f16(awhh[1][3], bh3, a1, 0, 0, 0);

            half2_t qa0 = __builtin_shufflevector(Qa[P], Qa[P], 0, 1);
            half2_t qa1 = __builtin_shufflevector(Qa[P], Qa[P], 2, 3);
            half2_t i01 = sigma_pk(pkrtz(a0[0], a0[1]) + qa0);
            half2_t i23 = sigma_pk(pkrtz(a0[2], a0[3]) + qa1);

            float4_t a2 = __builtin_amdgcn_mfma_f32_16x16x32_f16(awhh[2][0], bh0, zz, 0, 0, 0);
            a2 = __builtin_amdgcn_mfma_f32_16x16x32_f16(awhh[2][1], bh1, a2, 0, 0, 0);
            a2 = __builtin_amdgcn_mfma_f32_16x16x32_f16(awhh[2][2], bh2, a2, 0, 0, 0);
            a2 = __builtin_amdgcn_mfma_f32_16x16x32_f16(awhh[2][3], bh3, a2, 0, 0, 0);

            half2_t qa2 = __builtin_shufflevector(Qa[P], Qa[P], 4, 5);
            half2_t qa3 = __builtin_shufflevector(Qa[P], Qa[P], 6, 7);
            half2_t f01 = sigma_pk(pkrtz(a1[0], a1[1]) + qa2);
            half2_t f23 = sigma_pk(pkrtz(a1[2], a1[3]) + qa3);

            float4_t a3 = __builtin_amdgcn_mfma_f32_16x16x32_f16(awhh[3][0], bh0, zz, 0, 0, 0);
            a3 = __builtin_amdgcn_mfma_f32_16x16x32_f16(awhh[3][1], bh1, a3, 0, 0, 0);
            a3 = __builtin_amdgcn_mfma_f32_16x16x32_f16(awhh[3][2], bh2, a3, 0, 0, 0);
            a3 = __builtin_amdgcn_mfma_f32_16x16x32_f16(awhh[3][3], bh3, a3, 0, 0, 0);

            half2_t qb0 = __builtin_shufflevector(Qb[P], Qb[P], 0, 1);
            half2_t qb1 = __builtin_shufflevector(Qb[P], Qb[P], 2, 3);
            half2_t g01 = tanh_pk(pkrtz(a2[0], a2[1]) + qb0);
            half2_t g23 = tanh_pk(pkrtz(a2[2], a2[3]) + qb1);

            half2_t qb2 = __builtin_shufflevector(Qb[P], Qb[P], 4, 5);
            half2_t qb3 = __builtin_shufflevector(Qb[P], Qb[P], 6, 7);
            half2_t o01 = sigma_pk(pkrtz(a3[0], a3[1]) + qb2);
            half2_t o23 = sigma_pk(pkrtz(a3[2], a3[3]) + qb3);

            c01 = f01 * c01 + i01 * g01;
            c23 = f23 * c23 + i23 * g23;
            half2_t h01 = o01 * tanh_pk(c01);
            half2_t h23 = o23 * tanh_pk(c23);
            hm01 = __builtin_elementwise_max(hm01, h01);
            hm23 = __builtin_elementwise_max(hm23, h23);

            half4_t hv4;
            hv4[0] = h01[0]; hv4[1] = h01[1]; hv4[2] = h23[0]; hv4[3] = h23[1];
            *(half4_t*)&hsm[1 - (P & 1)][wbase] = hv4;

            __builtin_amdgcn_sched_group_barrier(0x100, 4, 0);  // bh0..3
            __builtin_amdgcn_sched_group_barrier(0x008, 4, 0);  // acc0 chain
            __builtin_amdgcn_sched_group_barrier(0x008, 4, 0);  // acc1 chain
            __builtin_amdgcn_sched_group_barrier(0x002, 22, 0); // i acts
            __builtin_amdgcn_sched_group_barrier(0x008, 4, 0);  // acc2 chain
            __builtin_amdgcn_sched_group_barrier(0x002, 22, 0); // f acts
            __builtin_amdgcn_sched_group_barrier(0x008, 4, 0);  // acc3 chain
            __builtin_amdgcn_sched_group_barrier(0x002, 22, 0); // g acts

            wg_barrier_lds();
        }
    }

    float4 o;
    o.x = (float)hm01[0]; o.y = (float)hm01[1];
    o.z = (float)hm23[0]; o.w = (float)hm23[1];
    *(float4*)&pooled[(size_t)(bg * 16 + lm) * 256 + dir * HH + w * 16 + lq * 4] = o;
}

// ---- kernel 3: pooled (128,256) -> relu(W1·+b1) -> sigmoid(W2·+b2) -> (128,1)
__global__ __launch_bounds__(64) void mlp_kernel(
    const float* __restrict__ pooled, const float* __restrict__ W1,
    const float* __restrict__ b1, const float* __restrict__ W2,
    const float* __restrict__ b2, float* __restrict__ out)
{
    const int b = blockIdx.x;
    const int j = threadIdx.x;
    const float4* p = (const float4*)(pooled + (size_t)b * 256);
    const float4* wv = (const float4*)(W1 + (size_t)j * 256);
    float s = 0.0f;
    #pragma unroll
    for (int q = 0; q < 64; ++q) {
        float4 pv = p[q];
        float4 ww = wv[q];
        s += pv.x * ww.x + pv.y * ww.y + pv.z * ww.z + pv.w * ww.w;
    }
    s += b1[j];
    s = fmaxf(s, 0.0f);
    float v = W2[j] * s;
    #pragma unroll
    for (int off = 32; off; off >>= 1) v += __shfl_down(v, off);
    if (j == 0) out[b] = 1.0f / (1.0f + __expf(-(v + b2[0])));
}

extern "C" void kernel_launch(void* const* d_in, const int* in_sizes, int n_in,
                              void* d_out, int out_size, void* d_ws, size_t ws_size,
                              hipStream_t stream) {
    const int*   x     = (const int*)d_in[0];
    const float* emb   = (const float*)d_in[1];
    const float* Wih_f = (const float*)d_in[2];
    const float* Whh_f = (const float*)d_in[3];
    const float* bih_f = (const float*)d_in[4];
    const float* bhh_f = (const float*)d_in[5];
    const float* Wih_b = (const float*)d_in[6];
    const float* Whh_b = (const float*)d_in[7];
    const float* bih_b = (const float*)d_in[8];
    const float* bhh_b = (const float*)d_in[9];
    const float* W1    = (const float*)d_in[10];
    const float* b1    = (const float*)d_in[11];
    const float* W2    = (const float*)d_in[12];
    const float* b2    = (const float*)d_in[13];
    float* out = (float*)d_out;

    char* ws = (char*)d_ws;
    float*    pooled = (float*)ws;                 // 128 KB
    _Float16* xp     = (_Float16*)(ws + 131072);   // 134.2 MB

    hipLaunchKernelGGL(xp_gemm_kernel, dim3(16, 16), dim3(512), 0, stream,
                       x, emb, Wih_f, bih_f, bhh_f, Wih_b, bih_b, bhh_b, xp);
    hipLaunchKernelGGL(bilstm_rec_kernel, dim3(16), dim3(512), 0, stream,
                       xp, Whh_f, Whh_b, pooled);
    hipLaunchKernelGGL(mlp_kernel, dim3(128), dim3(64), 0, stream,
                       pooled, W1, b1, W2, b2, out);
}